// Round 16
// baseline (942.446 us; speedup 1.0000x reference)
//
#include <hip/hip_runtime.h>
#include <hip/hip_bf16.h>
#include <stdint.h>

#define HSZ 2048
#define PRIME 500009u
#define CHUNK 64        // K-floats per staged chunk (256 B/row)
#define NCH 32          // 2048 / 64
#define WAVE_REG 16384  // per-wave staging region: 2 bufs x (4KB hidden + 4KB Wg)
#define IDXOFF 65536
#define A_OFF 0         // A_lds[36][264] bf16 = 19008 B
#define E36_OFF 19008   // emb36[36][36] f32  = 5184 B
#define GE_OFF 24192    // ge_lds[32][40] bf16 = 2560 B

typedef __attribute__((ext_vector_type(8))) short short8;
typedef __attribute__((ext_vector_type(4))) float f32x4;
typedef __attribute__((ext_vector_type(4))) unsigned uint4v;
typedef __attribute__((ext_vector_type(2))) unsigned uint2v;

#define MEMFENCE asm volatile("" ::: "memory")
#define BARRIER() do { MEMFENCE; __builtin_amdgcn_s_barrier(); MEMFENCE; } while (0)
#define WAIT_LGKM0 asm volatile("s_waitcnt lgkmcnt(0)" ::: "memory")
#define WAIT_VM(n) asm volatile("s_waitcnt vmcnt(" #n ")" ::: "memory")

__device__ __forceinline__ unsigned pk2(float x, float y) {
  __hip_bfloat162 h = __float22bfloat162_rn(make_float2(x, y));
  return *reinterpret_cast<unsigned*>(&h);
}
__device__ __forceinline__ short f2bf(float f) {
  __hip_bfloat16 h = __float2bfloat16(f);
  return *reinterpret_cast<short*>(&h);
}
__device__ __forceinline__ short8 pack8(float4 a, float4 b) {
  uint4v u = {pk2(a.x, a.y), pk2(a.z, a.w), pk2(b.x, b.y), pk2(b.z, b.w)};
  return __builtin_bit_cast(short8, u);
}
__device__ __forceinline__ short8 load8_bf(const float* __restrict__ p) {
  float4 a = *reinterpret_cast<const float4*>(p);
  float4 b = *reinterpret_cast<const float4*>(p + 4);
  return pack8(a, b);
}
__device__ __forceinline__ void gload_lds16(const float* g, void* l) {
  __builtin_amdgcn_global_load_lds(
      (const __attribute__((address_space(1))) void*)g,
      (__attribute__((address_space(3))) void*)l, 16, 0, 0);
}

// ====== R15 kernel, phase-amplified: MLP section x MR, out section x OR ======
// MR/OR == 1 reproduces R15 exactly. Diagnostic round: base<1,1>, <17,1>, <1,17>
// launched back-to-back; amplified dispatches surface in rocprof top-5 with
// counters; dur deltas give per-phase wall time.
template <int MR, int OR>
__global__ __launch_bounds__(256, 2) void engram_k(
    const int* __restrict__ ids, const int* __restrict__ mapping,
    const unsigned* __restrict__ mult, const float* __restrict__ table,
    const float* __restrict__ Wh, const float* __restrict__ hidden,
    const float* __restrict__ cw, const float* __restrict__ cb,
    const float* __restrict__ Wg, const float* __restrict__ Wo,
    float* __restrict__ out) {
  __shared__ __align__(16) char smem[IDXOFF + 1152];
  int* idx_lds = (int*)(smem + IDXOFF);
  short(*A_lds)[264] = (short(*)[264])(smem + A_OFF);
  float(*emb36)[36] = (float(*)[36])(smem + E36_OFF);
  short(*ge_lds)[40] = (short(*)[40])(smem + GE_OFF);

  const int tid = threadIdx.x;
  const int wid = tid >> 6, lane = tid & 63;
  const int l16 = lane & 15, q = lane >> 4;
  const int t0 = blockIdx.x * 32;
  const int tt = wid >> 1, ee = wid & 1;

  char* wavebase = smem + wid * WAVE_REG;

  auto STAGE = [&](int kc) {
    char* hb = wavebase + (kc & 1) * 8192;
#pragma unroll
    for (int j = 0; j < 4; ++j) {
      int r = j * 4 + q;
      unsigned c4 = (((unsigned)l16 * 16u) ^ (((unsigned)r & 7u) << 4)) >> 2;
      gload_lds16(hidden + (size_t)(t0 + tt * 16 + r) * HSZ + kc * CHUNK + c4,
                  hb + j * 1024);
    }
#pragma unroll
    for (int j = 0; j < 4; ++j) {
      int r = j * 4 + q;
      unsigned c4 = (((unsigned)l16 * 16u) ^ (((unsigned)r & 7u) << 4)) >> 2;
      gload_lds16(Wg + (size_t)(ee * 16 + r) * HSZ + kc * CHUNK + c4,
                  hb + 4096 + j * 1024);
    }
  };

  // ---- 1) hash ----
#pragma unroll
  for (int p = 0; p < 2; ++p) {
    int hh = p * 256 + tid;
    if (hh < 288) {
      int slot = hh >> 3, head = hh & 7;
      int tg = t0 - 4 + slot;
      if (tg < 0) tg = 0;
      int b = tg >> 12, s = tg & 4095;
      const int* idb = ids + (b << 12);
      int s1 = s + 1 > 4095 ? 4095 : s + 1;
      int s2 = s + 2 > 4095 ? 4095 : s + 2;
      uint64_t c0 = (unsigned)mapping[idb[s]];
      uint64_t c1 = (unsigned)mapping[idb[s1]];
      uint64_t c2 = (unsigned)mapping[idb[s2]];
      int mb = head * 3;
      uint64_t h = (c0 * (uint64_t)mult[mb]) ^ (c1 * (uint64_t)mult[mb + 1]);
      if (head >= 4) h ^= c2 * (uint64_t)mult[mb + 2];
      idx_lds[hh] = (int)((unsigned)(h % PRIME) + (unsigned)head * PRIME);
    }
  }
  WAIT_LGKM0; BARRIER();

  // ---- 2) gather held in VGPRs ----
  float4 g[9];
#pragma unroll
  for (int p = 0; p < 9; ++p) {
    int task = p * 256 + tid;
    int r = task >> 3, c4 = (task & 7) * 4;
    int row = idx_lds[r];
    g[p] = *reinterpret_cast<const float4*>(table + (size_t)row * 32 + c4);
  }

  // ---- 3) prologue staging (rep 0) ----
  STAGE(0);
  STAGE(1);

  // ---- 4) gate MLP: barrier-free, wave-private; repeated MR times ----
  const unsigned swz = ((unsigned)l16 & 7u) << 4;
  const char* hrow = wavebase + l16 * 256;
  const char* wrow = wavebase + 4096 + l16 * 256;
  const unsigned x0 = q * 32u;
  f32x4 acc;

  for (int rep = 0; rep < MR; ++rep) {
    if (rep > 0) { STAGE(0); STAGE(1); }  // prior rep's ds_reads all retired
    acc = f32x4{0.f, 0.f, 0.f, 0.f};

    auto MLP_ITER = [&](int kc, bool stage_next) {
      const char* hb = hrow + (kc & 1) * 8192;
      const char* wb = wrow + (kc & 1) * 8192;
      float4 a0 = *reinterpret_cast<const float4*>(hb + (x0 ^ swz));
      float4 a1 = *reinterpret_cast<const float4*>(hb + ((x0 + 16) ^ swz));
      float4 a2 = *reinterpret_cast<const float4*>(hb + ((x0 + 128) ^ swz));
      float4 a3 = *reinterpret_cast<const float4*>(hb + ((x0 + 144) ^ swz));
      float4 b0 = *reinterpret_cast<const float4*>(wb + (x0 ^ swz));
      float4 b1 = *reinterpret_cast<const float4*>(wb + ((x0 + 16) ^ swz));
      float4 b2 = *reinterpret_cast<const float4*>(wb + ((x0 + 128) ^ swz));
      float4 b3 = *reinterpret_cast<const float4*>(wb + ((x0 + 144) ^ swz));
      short8 A0 = pack8(a0, a1), A1 = pack8(a2, a3);
      short8 B0 = pack8(b0, b1), B1 = pack8(b2, b3);
      WAIT_LGKM0;
      if (stage_next) STAGE(kc + 2);
      acc = __builtin_amdgcn_mfma_f32_16x16x32_bf16(A0, B0, acc, 0, 0, 0);
      acc = __builtin_amdgcn_mfma_f32_16x16x32_bf16(A1, B1, acc, 0, 0, 0);
    };

    for (int kc = 0; kc < NCH - 1; ++kc) {
      WAIT_VM(8);
      MLP_ITER(kc, kc < NCH - 2);
    }
    { WAIT_VM(0); MLP_ITER(NCH - 1, false); }

    // keep this rep's MFMA chain live (anti-DCE, rule #17)
    float k0 = acc[0], k1 = acc[1], k2 = acc[2], k3 = acc[3];
    asm volatile("" : "+v"(k0), "+v"(k1), "+v"(k2), "+v"(k3));
    acc[0] = k0; acc[1] = k1; acc[2] = k2; acc[3] = k3;
  }

  // ---- 5) gathered rows -> A_lds bf16 ----
  BARRIER();
#pragma unroll
  for (int p = 0; p < 9; ++p) {
    int task = p * 256 + tid;
    int r = task >> 3, c4 = (task & 7) * 4;
    uint2v pk = {pk2(g[p].x, g[p].y), pk2(g[p].z, g[p].w)};
    *reinterpret_cast<uint2v*>(&A_lds[r >> 3][(r & 7) * 32 + c4]) = pk;
  }
  WAIT_LGKM0; BARRIER();

  // ---- 6) emb0 MFMA ----
  for (int job = wid; job < 6; job += 4) {
    int jt = job >> 1;
    int base = (jt == 0) ? 0 : (jt == 1) ? 16 : 20;
    int e0 = (job & 1) * 16;
    f32x4 ac = {0.f, 0.f, 0.f, 0.f};
#pragma unroll
    for (int ks = 0; ks < 8; ++ks) {
      short8 wf = load8_bf(Wh + (size_t)(e0 + l16) * 256 + ks * 32 + q * 8);
      short8 a = *reinterpret_cast<const short8*>(&A_lds[base + l16][ks * 32 + q * 8]);
      ac = __builtin_amdgcn_mfma_f32_16x16x32_bf16(wf, a, ac, 0, 0, 0);
    }
    if (jt != 2 || l16 >= 12)
      *reinterpret_cast<f32x4*>(&emb36[base + l16][e0 + q * 4]) = ac;
  }
  WAIT_LGKM0; BARRIER();

  // ---- 7) conv + sigmoid fused ----
  {
    int c = ee * 16 + l16;
    float4 cwv = *reinterpret_cast<const float4*>(cw + c * 4);
    float cbv = cb[c];
#pragma unroll
    for (int j = 0; j < 4; ++j) {
      int r = tt * 16 + q * 4 + j;
      int s = (t0 & 4095) + r;
      float v = cbv;
#pragma unroll
      for (int j2 = 0; j2 < 4; ++j2)
        if (s - 3 + j2 >= 0) v += cwv[j2] * emb36[r + 1 + j2][c];
      float gt = 1.f / (1.f + __expf(-acc[j]));
      ge_lds[r][c] = f2bf(gt * v);
    }
  }
  WAIT_LGKM0; BARRIER();

  // ---- 8) out = ge @ Wo.T; repeated OR times (idempotent rewrites) ----
  short8 Af0 = *reinterpret_cast<const short8*>(&ge_lds[l16][q * 8]);
  short8 Af1 = *reinterpret_cast<const short8*>(&ge_lds[16 + l16][q * 8]);
  float* orow0 = out + (size_t)(t0 + l16) * HSZ;
  float* orow1 = out + (size_t)(t0 + 16 + l16) * HSZ;
  int hbase = wid * 512;
  for (int orp = 0; orp < OR; ++orp) {
#pragma unroll 4
    for (int ht = 0; ht < 32; ++ht) {
      int h0 = hbase + ht * 16;
      short8 aw = load8_bf(Wo + (size_t)(h0 + l16) * 32 + q * 8);
      f32x4 z = {0.f, 0.f, 0.f, 0.f};
      f32x4 o0 = __builtin_amdgcn_mfma_f32_16x16x32_bf16(aw, Af0, z, 0, 0, 0);
      f32x4 o1 = __builtin_amdgcn_mfma_f32_16x16x32_bf16(aw, Af1, z, 0, 0, 0);
      *reinterpret_cast<f32x4*>(orow0 + h0 + q * 4) = o0;
      *reinterpret_cast<f32x4*>(orow1 + h0 + q * 4) = o1;
    }
    MEMFENCE;  // rep boundary observable: blocks DSE/load-hoist across reps
  }
}

extern "C" void kernel_launch(void* const* d_in, const int* in_sizes, int n_in,
                              void* d_out, int out_size, void* d_ws, size_t ws_size,
                              hipStream_t stream) {
  const int* ids = (const int*)d_in[0];
  const float* hidden = (const float*)d_in[1];
  const int* mapping = (const int*)d_in[2];
  const unsigned* mult = (const unsigned*)d_in[3];
  const float* table = (const float*)d_in[4];
  const float* cw = (const float*)d_in[5];
  const float* cb = (const float*)d_in[6];
  const float* Wh = (const float*)d_in[7];
  const float* Wg = (const float*)d_in[8];
  const float* Wo = (const float*)d_in[9];
  float* out = (float*)d_out;

  // base (timing anchor), MLP-amplified, out-amplified — all write identical out
  engram_k<1, 1><<<512, 256, 0, stream>>>(ids, mapping, mult, table, Wh, hidden,
                                          cw, cb, Wg, Wo, out);
  engram_k<17, 1><<<512, 256, 0, stream>>>(ids, mapping, mult, table, Wh, hidden,
                                           cw, cb, Wg, Wo, out);
  engram_k<1, 17><<<512, 256, 0, stream>>>(ids, mapping, mult, table, Wh, hidden,
                                           cw, cb, Wg, Wo, out);
}

// Round 17
// 86.806 us; speedup vs baseline: 10.8569x; 10.8569x over previous
//
#include <hip/hip_runtime.h>
#include <hip/hip_bf16.h>
#include <stdint.h>

#define HSZ 2048
#define PRIME 500009u
#define CHUNK 32       // K-floats per staged chunk (128 B/row)
#define NCH 32         // 1024 (K-half) / 32
#define WAVE_REG 8192  // per-wave staging: 2 bufs x (2KB hidden + 2KB Wg)
#define IDXOFF 32768   // idx_lds[160] after the staging region
// post-MLP aliases into the (dead) staging region:
#define A_OFF 0        // A_lds[20][264] bf16 = 10560 B
#define E20_OFF 10560  // emb20[20][36] f32   = 2880 B
#define GE_OFF 13440   // ge_lds[16][40] bf16 = 1280 B
#define RED_OFF 14720  // accred[2][4][64] f32 = 2048 B (ends 16768 < 32768)

typedef __attribute__((ext_vector_type(8))) short short8;
typedef __attribute__((ext_vector_type(4))) float f32x4;
typedef __attribute__((ext_vector_type(4))) unsigned uint4v;
typedef __attribute__((ext_vector_type(2))) unsigned uint2v;

#define MEMFENCE asm volatile("" ::: "memory")
#define BARRIER() do { MEMFENCE; __builtin_amdgcn_s_barrier(); MEMFENCE; } while (0)
#define WAIT_LGKM0 asm volatile("s_waitcnt lgkmcnt(0)" ::: "memory")
#define WAIT_VM(n) asm volatile("s_waitcnt vmcnt(" #n ")" ::: "memory")

__device__ __forceinline__ unsigned pk2(float x, float y) {
  __hip_bfloat162 h = __float22bfloat162_rn(make_float2(x, y));
  return *reinterpret_cast<unsigned*>(&h);
}
__device__ __forceinline__ short f2bf(float f) {
  __hip_bfloat16 h = __float2bfloat16(f);
  return *reinterpret_cast<short*>(&h);
}
__device__ __forceinline__ short8 pack8(float4 a, float4 b) {
  uint4v u = {pk2(a.x, a.y), pk2(a.z, a.w), pk2(b.x, b.y), pk2(b.z, b.w)};
  return __builtin_bit_cast(short8, u);
}
__device__ __forceinline__ short8 load8_bf(const float* __restrict__ p) {
  float4 a = *reinterpret_cast<const float4*>(p);
  float4 b = *reinterpret_cast<const float4*>(p + 4);
  return pack8(a, b);
}
__device__ __forceinline__ void gload_lds16(const float* g, void* l) {
  __builtin_amdgcn_global_load_lds(
      (const __attribute__((address_space(1))) void*)g,
      (__attribute__((address_space(3))) void*)l, 16, 0, 0);
}

// ============ fused kernel: 1024 blocks x 256 threads, 16 tokens/block ============
// R15's barrier-free wave-private MLP at 4 blocks/CU (33.4 KB LDS, lb(256,4)):
// 16 independent wave pipelines per CU. Wave (ee,kh) owns e-tile x K-half;
// CHUNK=32, 4 stage instrs/chunk, exact per-wave counted vmcnt(4)/0.
__global__ __launch_bounds__(256, 4) void engram_fused(
    const int* __restrict__ ids, const int* __restrict__ mapping,
    const unsigned* __restrict__ mult, const float* __restrict__ table,
    const float* __restrict__ Wh, const float* __restrict__ hidden,
    const float* __restrict__ cw, const float* __restrict__ cb,
    const float* __restrict__ Wg, const float* __restrict__ Wo,
    float* __restrict__ out) {
  __shared__ __align__(16) char smem[IDXOFF + 640];  // 33,408 B -> 4 blocks/CU
  int* idx_lds = (int*)(smem + IDXOFF);
  short(*A_lds)[264] = (short(*)[264])(smem + A_OFF);
  float(*emb20)[36] = (float(*)[36])(smem + E20_OFF);
  short(*ge_lds)[40] = (short(*)[40])(smem + GE_OFF);
  float(*accred)[4][64] = (float(*)[4][64])(smem + RED_OFF);

  const int tid = threadIdx.x;
  const int wid = tid >> 6, lane = tid & 63;
  const int l16 = lane & 15, q = lane >> 4;
  const int t0 = blockIdx.x * 16;
  const int ee = wid & 1, kh = wid >> 1;  // e-tile / K-half of this wave

  char* wavebase = smem + wid * WAVE_REG;

  // stage this wave's chunk kc: 16 hidden rows (tokens t0..t0+15) + 16 Wg rows
  // (ee*16..), 128 B/row, K-cols [kh*1024 + kc*32, +32). 1 instr = 8 rows.
  // LDS dest linear; global src col byte-XOR-swizzled by ((r&7)<<4); reads match.
  auto STAGE = [&](int kc) {
    char* hb = wavebase + (kc & 1) * 4096;
#pragma unroll
    for (int j = 0; j < 2; ++j) {
      int r = j * 8 + (lane >> 3);
      unsigned c4 = ((((unsigned)lane & 7u) * 16u) ^ (((unsigned)r & 7u) << 4)) >> 2;
      gload_lds16(hidden + (size_t)(t0 + r) * HSZ + kh * 1024 + kc * CHUNK + c4,
                  hb + j * 1024);
    }
#pragma unroll
    for (int j = 0; j < 2; ++j) {
      int r = j * 8 + (lane >> 3);
      unsigned c4 = ((((unsigned)lane & 7u) * 16u) ^ (((unsigned)r & 7u) << 4)) >> 2;
      gload_lds16(Wg + (size_t)(ee * 16 + r) * HSZ + kh * 1024 + kc * CHUNK + c4,
                  hb + 2048 + j * 1024);
    }
  };

  // ---- 1) hash: 20 slots x 8 heads = 160; slot s = token t0-4+s (clamped) ----
  if (tid < 160) {
    int slot = tid >> 3, head = tid & 7;
    int tg = t0 - 4 + slot;
    if (tg < 0) tg = 0;
    int b = tg >> 12, s = tg & 4095;
    const int* idb = ids + (b << 12);
    int s1 = s + 1 > 4095 ? 4095 : s + 1;
    int s2 = s + 2 > 4095 ? 4095 : s + 2;
    uint64_t c0 = (unsigned)mapping[idb[s]];
    uint64_t c1 = (unsigned)mapping[idb[s1]];
    uint64_t c2 = (unsigned)mapping[idb[s2]];
    int mb = head * 3;  // multipliers row-major [2][4][3]
    uint64_t h = (c0 * (uint64_t)mult[mb]) ^ (c1 * (uint64_t)mult[mb + 1]);
    if (head >= 4) h ^= c2 * (uint64_t)mult[mb + 2];
    idx_lds[tid] = (int)((unsigned)(h % PRIME) + (unsigned)head * PRIME);
  }
  WAIT_LGKM0; BARRIER();

  // ---- 2) issue gather: 160 rows x 128 B, 5 float4/thread, HELD in VGPRs ----
  float4 g[5];
#pragma unroll
  for (int p = 0; p < 5; ++p) {
    int task = p * 256 + tid;  // 1280 tasks = 160 rows x 8 lane-groups
    int r = task >> 3, c4 = (task & 7) * 4;
    int row = idx_lds[r];
    g[p] = *reinterpret_cast<const float4*>(table + (size_t)row * 32 + c4);
  }

  // ---- 3) prologue: this wave's chunks 0,1 in flight ----
  STAGE(0);
  STAGE(1);

  // ---- 4) gate MLP: barrier-free, wave-private; K-half per wave ----
  const unsigned swz = ((unsigned)l16 & 7u) << 4;
  const char* hrow = wavebase + l16 * 128;
  const char* wrow = wavebase + 2048 + l16 * 128;
  const unsigned x0 = q * 32u;
  f32x4 acc = {0.f, 0.f, 0.f, 0.f};

  auto MLP_ITER = [&](int kc, bool stage_next) {
    const char* hb = hrow + (kc & 1) * 4096;
    const char* wb = wrow + (kc & 1) * 4096;
    float4 a0 = *reinterpret_cast<const float4*>(hb + (x0 ^ swz));
    float4 a1 = *reinterpret_cast<const float4*>(hb + ((x0 + 16) ^ swz));
    float4 b0 = *reinterpret_cast<const float4*>(wb + (x0 ^ swz));
    float4 b1 = *reinterpret_cast<const float4*>(wb + ((x0 + 16) ^ swz));
    short8 A0 = pack8(a0, a1);
    short8 B0 = pack8(b0, b1);
    WAIT_LGKM0;                    // our ds_reads of chunk kc are in regs
    if (stage_next) STAGE(kc + 2); // safe to overwrite buf[kc&1]
    acc = __builtin_amdgcn_mfma_f32_16x16x32_bf16(A0, B0, acc, 0, 0, 0);
  };

  for (int kc = 0; kc < NCH - 1; ++kc) {
    WAIT_VM(4);  // exact: stage(kc) landed; stage(kc+1)'s 4 instrs may fly
    MLP_ITER(kc, kc < NCH - 2);  // (iter 0 also retires the 5 gather instrs)
  }
  { WAIT_VM(0); MLP_ITER(NCH - 1, false); }  // final chunk, full drain

  // ---- 5) staging region dead -> gathered rows to A_lds bf16 + accred ----
  BARRIER();
#pragma unroll
  for (int p = 0; p < 5; ++p) {
    int task = p * 256 + tid;
    int r = task >> 3, c4 = (task & 7) * 4;
    uint2v pk = {pk2(g[p].x, g[p].y), pk2(g[p].z, g[p].w)};
    *reinterpret_cast<uint2v*>(&A_lds[r >> 3][(r & 7) * 32 + c4]) = pk;
  }
  if (kh == 1) {
#pragma unroll
    for (int j = 0; j < 4; ++j) accred[ee][j][lane] = acc[j];
  }
  WAIT_LGKM0; BARRIER();

  // ---- 6) emb0 MFMA: 2 slot-tiles (bases 0,4) x 2 e-tiles = 4 jobs, 1/wave ----
  {
    int jt = kh;  // reuse wave coords: jt = wid>>1, e-tile = ee
    int base = jt ? 4 : 0;
    int e0 = ee * 16;
    f32x4 ac = {0.f, 0.f, 0.f, 0.f};
#pragma unroll
    for (int ks = 0; ks < 8; ++ks) {
      short8 wf = load8_bf(Wh + (size_t)(e0 + l16) * 256 + ks * 32 + q * 8);
      short8 a = *reinterpret_cast<const short8*>(&A_lds[base + l16][ks * 32 + q * 8]);
      ac = __builtin_amdgcn_mfma_f32_16x16x32_bf16(wf, a, ac, 0, 0, 0);
    }
    // D: col=slot(l16), row=e(q*4+j); tile base 4 writes only slots 16..19
    if (jt == 0 || l16 >= 12)
      *reinterpret_cast<f32x4*>(&emb20[base + l16][e0 + q * 4]) = ac;
  }
  WAIT_LGKM0; BARRIER();

  // ---- 7) reduce + conv + sigmoid fused (kh==0 waves own the full 16x32 gate) ----
  if (kh == 0) {
    int c = ee * 16 + l16;
    float4 cwv = *reinterpret_cast<const float4*>(cw + c * 4);
    float cbv = cb[c];
#pragma unroll
    for (int j = 0; j < 4; ++j) {
      int r = q * 4 + j;                    // token row (D: col=gate-e, row=token)
      float s = acc[j] + accred[ee][j][lane];
      int sp = (t0 & 4095) + r;
      float v = cbv;
#pragma unroll
      for (int j2 = 0; j2 < 4; ++j2)
        if (sp - 3 + j2 >= 0) v += cwv[j2] * emb20[r + 1 + j2][c];
      float gt = 1.f / (1.f + __expf(-s));
      ge_lds[r][c] = f2bf(gt * v);
    }
  }
  WAIT_LGKM0; BARRIER();

  // ---- 8) out[t,h] = ge @ Wo.T (swapped -> float4 stores); 512 h-cols/wave ----
  short8 Af = *reinterpret_cast<const short8*>(&ge_lds[l16][q * 8]);
  float* orow = out + (size_t)(t0 + l16) * HSZ;
#pragma unroll 4
  for (int ht = 0; ht < 32; ++ht) {
    int h0 = wid * 512 + ht * 16;
    short8 aw = load8_bf(Wo + (size_t)(h0 + l16) * 32 + q * 8);
    f32x4 z = {0.f, 0.f, 0.f, 0.f};
    f32x4 o = __builtin_amdgcn_mfma_f32_16x16x32_bf16(aw, Af, z, 0, 0, 0);
    *reinterpret_cast<f32x4*>(orow + h0 + q * 4) = o;  // D: col=token, row=h
  }
}

extern "C" void kernel_launch(void* const* d_in, const int* in_sizes, int n_in,
                              void* d_out, int out_size, void* d_ws, size_t ws_size,
                              hipStream_t stream) {
  const int* ids = (const int*)d_in[0];
  const float* hidden = (const float*)d_in[1];
  const int* mapping = (const int*)d_in[2];
  const unsigned* mult = (const unsigned*)d_in[3];  // delivered as int32; low bits exact
  const float* table = (const float*)d_in[4];
  const float* cw = (const float*)d_in[5];
  const float* cb = (const float*)d_in[6];
  const float* Wh = (const float*)d_in[7];
  const float* Wg = (const float*)d_in[8];
  const float* Wo = (const float*)d_in[9];
  float* out = (float*)d_out;

  engram_fused<<<1024, 256, 0, stream>>>(ids, mapping, mult, table, Wh, hidden,
                                         cw, cb, Wg, Wo, out);
}